// Round 8
// baseline (801.073 us; speedup 1.0000x reference)
//
#include <hip/hip_runtime.h>

typedef unsigned short u16;
typedef unsigned int   u32;
typedef unsigned long long u64;

#define F 128
#define F3 384
#define TA 32          // atoms per MLP block
#define PAD 36         // padded LDS row (floats)
#define ROW 768        // xm12 row length in u16 (1536 B): 64 pairs x 12

__device__ __forceinline__ float bf2f(u16 v) {
    union { u32 u; float f; } c; c.u = ((u32)v) << 16; return c.f;
}
__device__ __forceinline__ u16 f2bf(float f) {
    union { float fv; u32 u; } c; c.fv = f;
    u32 u = c.u;
    return (u16)((u + 0x7fffu + ((u >> 16) & 1u)) >> 16);   // round-nearest-even
}
__device__ __forceinline__ float u2f(u32 v) {
    union { u32 u; float f; } c; c.u = v; return c.f;
}
__device__ __forceinline__ u32 f2u(float v) {
    union { float f; u32 u; } c; c.f = v; return c.u;
}
__device__ __forceinline__ u32 pk(float a, float b) {
    return ((u32)f2bf(b) << 16) | f2bf(a);
}

// dtype-generic accessors: BF=true -> bf16 (u16) arrays, false -> f32 arrays
template<bool BF> __device__ __forceinline__ float LD(const void* p, size_t i) {
    return BF ? bf2f(((const u16*)p)[i]) : ((const float*)p)[i];
}
template<bool BF> __device__ __forceinline__ float2 LD2(const void* p, size_t i) {
    if (BF) {
        u32 v = *(const u32*)((const u16*)p + i);
        float2 r; r.x = bf2f((u16)(v & 0xffff)); r.y = bf2f((u16)(v >> 16)); return r;
    }
    return *(const float2*)((const float*)p + i);
}
template<bool BF> __device__ __forceinline__ void ST2(void* p, size_t i, float2 v) {
    if (BF) { *(u32*)((u16*)p + i) = pk(v.x, v.y); }
    else    { *(float2*)((float*)p + i) = v; }
}
template<bool BF> __device__ __forceinline__ float4 LD4(const void* p, size_t i) {
    if (BF) {
        uint2 v = *(const uint2*)((const u16*)p + i);
        float4 r;
        r.x = bf2f((u16)(v.x & 0xffff)); r.y = bf2f((u16)(v.x >> 16));
        r.z = bf2f((u16)(v.y & 0xffff)); r.w = bf2f((u16)(v.y >> 16));
        return r;
    }
    return *(const float4*)((const float*)p + i);
}
// nontemporal variants (touch-once streams)
template<bool BF> __device__ __forceinline__ void NTST2(void* p, size_t i, float2 v) {
    if (BF) {
        u32 o = pk(v.x, v.y);
        __builtin_nontemporal_store(o, (u32*)((u16*)p + i));
    } else {
        u64 o = ((u64)f2u(v.y) << 32) | f2u(v.x);
        __builtin_nontemporal_store(o, (u64*)((float*)p + i));
    }
}

// ---------------------------------------------------------------------------
// Dtype detector (proven)
// ---------------------------------------------------------------------------
__global__ __launch_bounds__(256) void detect_kernel(const void* q, int* flag) {
    __shared__ int cnt;
    if (threadIdx.x == 0) cnt = 0;
    __syncthreads();
    const u16* p = (const u16*)q;
    int c = 0;
    for (int i = threadIdx.x; i < 1024; i += 256) {
        u16 v = p[2 * i];
        int e = (v >> 7) & 0xFF;
        if (e >= 100 && e <= 150) c++;
    }
    atomicAdd(&cnt, c);
    __syncthreads();
    if (threadIdx.x == 0) *flag = (cnt > 512) ? 1 : 0;
}

// ---------------------------------------------------------------------------
// mu -> packed half of xm12: entries [6..11] of each 12-u16 pair-block
// ---------------------------------------------------------------------------
template<bool BF>
__device__ void mu12_body(const void* mu, u16* xm12, int n_atoms) {
    int a = blockIdx.x * 4 + (threadIdx.x >> 6);
    int p = threadIdx.x & 63;
    if (a >= n_atoms) return;
    float2 m0 = LD2<BF>(mu, (size_t)a * F3 + 2 * p);
    float2 m1 = LD2<BF>(mu, (size_t)a * F3 + 128 + 2 * p);
    float2 m2 = LD2<BF>(mu, (size_t)a * F3 + 256 + 2 * p);
    u16* base = xm12 + (size_t)a * ROW + p * 12;
    *(u32*)(base + 6) = pk(m0.x, m0.y);
    *(uint2*)(base + 8) = make_uint2(pk(m1.x, m1.y), pk(m2.x, m2.y));
}
__global__ __launch_bounds__(256) void mu12_kernel(const void* mu, u16* xm12,
                                                   int n_atoms, const int* flag) {
    if (*flag) mu12_body<true >(mu, xm12, n_atoms);
    else       mu12_body<false>(mu, xm12, n_atoms);
}

// ---------------------------------------------------------------------------
// Full MLP -> packed half of xm12: entries [0..5] (xq,xR,xm) of each pair-block
// ---------------------------------------------------------------------------
template<bool BF>
__device__ void mlpfull_body(const void* q, const void* W1, const void* b1,
                             const void* W2, const void* b2,
                             u16* __restrict__ xm12, int n_atoms)
{
    __shared__ float qT[F][PAD];
    __shared__ float hT[F][PAD];

    const int tid = threadIdx.x;
    const int a0  = blockIdx.x * TA;
    const int c4  = (tid & 31) * 4;
    const int r4  = (tid >> 5) * 4;

    for (int i = tid; i < TA * F / 8; i += 256) {
        int a = i >> 4, f0 = (i & 15) * 8;
        float4 v0, v1;
        if (a0 + a < n_atoms) {
            v0 = LD4<BF>(q, (size_t)(a0 + a) * F + f0);
            v1 = LD4<BF>(q, (size_t)(a0 + a) * F + f0 + 4);
        } else { v0 = v1 = make_float4(0, 0, 0, 0); }
        qT[f0 + 0][a] = v0.x; qT[f0 + 1][a] = v0.y; qT[f0 + 2][a] = v0.z; qT[f0 + 3][a] = v0.w;
        qT[f0 + 4][a] = v1.x; qT[f0 + 5][a] = v1.y; qT[f0 + 6][a] = v1.z; qT[f0 + 7][a] = v1.w;
    }
    __syncthreads();

    {
        float acc[4][4];
#pragma unroll
        for (int rr = 0; rr < 4; ++rr)
#pragma unroll
            for (int cc = 0; cc < 4; ++cc) acc[rr][cc] = 0.0f;

        for (int f = 0; f < F; ++f) {
            float4 qv = *(const float4*)&qT[f][r4];
            float4 w  = LD4<BF>(W1, (size_t)f * F + c4);
            float qa[4] = {qv.x, qv.y, qv.z, qv.w};
            float wa[4] = {w.x, w.y, w.z, w.w};
#pragma unroll
            for (int rr = 0; rr < 4; ++rr)
#pragma unroll
                for (int cc = 0; cc < 4; ++cc)
                    acc[rr][cc] += qa[rr] * wa[cc];
        }
#pragma unroll
        for (int cc = 0; cc < 4; ++cc) {
            float bb = LD<BF>(b1, c4 + cc);
#pragma unroll
            for (int rr = 0; rr < 4; ++rr) {
                float h = acc[rr][cc] + bb;
                hT[c4 + cc][r4 + rr] = h / (1.0f + __expf(-h));
            }
        }
    }
    __syncthreads();

    float xout[4][4][3];
#pragma unroll
    for (int cb = 0; cb < 3; ++cb) {
        float acc[4][4];
#pragma unroll
        for (int rr = 0; rr < 4; ++rr)
#pragma unroll
            for (int cc = 0; cc < 4; ++cc) acc[rr][cc] = 0.0f;

        for (int f = 0; f < F; ++f) {
            float4 hv = *(const float4*)&hT[f][r4];
            float4 w  = LD4<BF>(W2, (size_t)f * F3 + cb * F + c4);
            float ha[4] = {hv.x, hv.y, hv.z, hv.w};
            float wa[4] = {w.x, w.y, w.z, w.w};
#pragma unroll
            for (int rr = 0; rr < 4; ++rr)
#pragma unroll
                for (int cc = 0; cc < 4; ++cc)
                    acc[rr][cc] += ha[rr] * wa[cc];
        }
#pragma unroll
        for (int cc = 0; cc < 4; ++cc) {
            float bb = LD<BF>(b2, cb * F + c4 + cc);
#pragma unroll
            for (int rr = 0; rr < 4; ++rr)
                xout[rr][cc][cb] = acc[rr][cc] + bb;
        }
    }
#pragma unroll
    for (int rr = 0; rr < 4; ++rr) {
        int ga = a0 + r4 + rr;
        if (ga < n_atoms) {
            int p0 = c4 >> 1;
            u16* b0 = xm12 + (size_t)ga * ROW + p0 * 12;
            *(uint2*)(b0) = make_uint2(pk(xout[rr][0][0], xout[rr][1][0]),
                                       pk(xout[rr][0][1], xout[rr][1][1]));
            *(u32*)(b0 + 4) = pk(xout[rr][0][2], xout[rr][1][2]);
            u16* b1p = b0 + 12;
            *(uint2*)(b1p) = make_uint2(pk(xout[rr][2][0], xout[rr][3][0]),
                                        pk(xout[rr][2][1], xout[rr][3][1]));
            *(u32*)(b1p + 4) = pk(xout[rr][2][2], xout[rr][3][2]);
        }
    }
}
__global__ __launch_bounds__(256) void mlpfull_kernel(
    const void* q, const void* W1, const void* b1, const void* W2, const void* b2,
    u16* xm12, int n_atoms, const int* flag)
{
    if (*flag) mlpfull_body<true >(q, W1, b1, W2, b2, xm12, n_atoms);
    else       mlpfull_body<false>(q, W1, b1, W2, b2, xm12, n_atoms);
}

// ---------------------------------------------------------------------------
// CSR build
// ---------------------------------------------------------------------------
__global__ __launch_bounds__(256) void count_kernel(
    const int* __restrict__ idx_i, int* __restrict__ counts, int E)
{
    int e = blockIdx.x * 256 + threadIdx.x;
    if (e < E) atomicAdd(&counts[idx_i[e]], 1);
}

__global__ __launch_bounds__(1024) void scan_kernel(
    const int* __restrict__ counts, int* __restrict__ offsets, int n)
{
    __shared__ int buf[1024];
    const int t = threadIdx.x;
    const int m = (n + 1023) >> 10;
    const int i0 = t * m;
    int s = 0;
    for (int r = 0; r < m; ++r) {
        int i = i0 + r;
        if (i < n) s += counts[i];
    }
    buf[t] = s;
    __syncthreads();
    for (int off = 1; off < 1024; off <<= 1) {
        int add = (t >= off) ? buf[t - off] : 0;
        __syncthreads();
        buf[t] += add;
        __syncthreads();
    }
    int run = buf[t] - s;
    for (int r = 0; r < m; ++r) {
        int i = i0 + r;
        if (i < n) { offsets[i] = run; run += counts[i]; }
    }
    if (t == 1023) offsets[n] = buf[1023];
}

// ---------------------------------------------------------------------------
// scatter_w: 1 WAVE per edge. Sequential-read Wij[e] (full row, f32/bf16),
// convert to bf16, write to Wbf[pos] in CSR order (random full-line writes).
// Also emits ej4[pos] = {e, j, dir01_bf16, dir2_bf16}.
// ---------------------------------------------------------------------------
template<bool BF>
__device__ void scatter_w_body(const int* __restrict__ idx_i, const int* __restrict__ idx_j,
                               const void* __restrict__ dir, const void* __restrict__ Wij,
                               const int* __restrict__ offsets, int* __restrict__ cursor,
                               int4* __restrict__ ej4, u16* __restrict__ wbf, int E)
{
    int e    = blockIdx.x * 4 + (threadIdx.x >> 6);
    int lane = threadIdx.x & 63;
    if (e >= E) return;

    int pos = 0;
    if (lane == 0) {
        int i = idx_i[e];
        pos = offsets[i] + atomicAdd(&cursor[i], 1);
        float d0 = LD<BF>(dir, (size_t)e * 3 + 0);
        float d1 = LD<BF>(dir, (size_t)e * 3 + 1);
        float d2 = LD<BF>(dir, (size_t)e * 3 + 2);
        int4 v;
        v.x = e;
        v.y = idx_j[e];
        v.z = (int)pk(d0, d1);
        v.w = (int)(u32)f2bf(d2);
        ej4[pos] = v;
    }
    pos = __shfl(pos, 0, 64);

    const size_t fo = 2 * (size_t)lane;
    float2 wq = LD2<BF>(Wij, (size_t)e * F3 + fo);
    float2 wR = LD2<BF>(Wij, (size_t)e * F3 + 128 + fo);
    float2 wm = LD2<BF>(Wij, (size_t)e * F3 + 256 + fo);
    u16* row = wbf + (size_t)pos * F3;          // planar [3][128] bf16, 768 B
    *(u32*)(row + fo)       = pk(wq.x, wq.y);
    *(u32*)(row + 128 + fo) = pk(wR.x, wR.y);
    *(u32*)(row + 256 + fo) = pk(wm.x, wm.y);
}
__global__ __launch_bounds__(256) void scatter_w_kernel(
    const int* idx_i, const int* idx_j, const void* dir, const void* Wij,
    const int* offsets, int* cursor, int4* ej4, u16* wbf, int E, const int* flag)
{
    if (*flag) scatter_w_body<true >(idx_i, idx_j, dir, Wij, offsets, cursor, ej4, wbf, E);
    else       scatter_w_body<false>(idx_i, idx_j, dir, Wij, offsets, cursor, ej4, wbf, E);
}

// ---------------------------------------------------------------------------
// FUSED gather v3: Wbf read is SEQUENTIAL (CSR position order, NT);
// xm12 is the only random access (bf16, L3-resident working set).
// Per edge per lane: 3x u32 NT Wbf + 3x uint2 xm12.
// ---------------------------------------------------------------------------
template<bool BF>
__device__ void gfused_body(const void* q, const void* mu,
                            const u16* __restrict__ wbf,
                            const u16* __restrict__ xm12,
                            const int4* __restrict__ ej4,
                            const int* __restrict__ offsets,
                            void* out, int n_atoms, int E)
{
    int a    = blockIdx.x * 4 + (threadIdx.x >> 6);
    int lane = threadIdx.x & 63;
    if (a >= n_atoms) return;
    const size_t fo = 2 * lane;
    const size_t ob = (size_t)n_atoms * F;

    float2 sq = LD2<BF>(q, (size_t)a * F + fo);
    float2 s0 = LD2<BF>(mu, (size_t)a * F3 + fo);
    float2 s1 = LD2<BF>(mu, (size_t)a * F3 + 128 + fo);
    float2 s2 = LD2<BF>(mu, (size_t)a * F3 + 256 + fo);

    int k0 = offsets[a], k1 = offsets[a + 1];
    for (int kb = k0; kb < k1; kb += 64) {
        int cnt = k1 - kb; if (cnt > 64) cnt = 64;
        int j_r = 0, d01_r = 0, d2_r = 0;
        if (lane < cnt) {
            int4 t = ej4[kb + lane];
            j_r = t.y; if ((unsigned)j_r >= (unsigned)n_atoms) j_r = 0;
            d01_r = t.z; d2_r = t.w;
        }
#pragma unroll 4
        for (int c = 0; c < cnt; ++c) {
            int j   = __shfl(j_r, c, 64);
            int d01 = __shfl(d01_r, c, 64);
            int d2i = __shfl(d2_r, c, 64);
            float d0 = bf2f((u16)((u32)d01 & 0xffff));
            float d1 = bf2f((u16)((u32)d01 >> 16));
            float d2 = bf2f((u16)((u32)d2i & 0xffff));

            const u16* wrow = wbf + (size_t)(kb + c) * F3;   // sequential
            u32 wqv = __builtin_nontemporal_load((const u32*)(wrow + fo));
            u32 wRv = __builtin_nontemporal_load((const u32*)(wrow + 128 + fo));
            u32 wmv = __builtin_nontemporal_load((const u32*)(wrow + 256 + fo));

            const u16* row = xm12 + (size_t)j * ROW + lane * 12;
            uint2 v0 = *(const uint2*)(row);
            uint2 v1 = *(const uint2*)(row + 4);
            uint2 v2 = *(const uint2*)(row + 8);

            float wq0 = bf2f((u16)(wqv & 0xffff)), wq1 = bf2f((u16)(wqv >> 16));
            float wR0 = bf2f((u16)(wRv & 0xffff)), wR1 = bf2f((u16)(wRv >> 16));
            float wm0 = bf2f((u16)(wmv & 0xffff)), wm1 = bf2f((u16)(wmv >> 16));

            float xq0 = bf2f((u16)(v0.x & 0xffff)), xq1 = bf2f((u16)(v0.x >> 16));
            float xR0 = bf2f((u16)(v0.y & 0xffff)), xR1 = bf2f((u16)(v0.y >> 16));
            float xm0 = bf2f((u16)(v1.x & 0xffff)), xm1 = bf2f((u16)(v1.x >> 16));
            float m00 = bf2f((u16)(v1.y & 0xffff)), m01 = bf2f((u16)(v1.y >> 16));
            float m10 = bf2f((u16)(v2.x & 0xffff)), m11 = bf2f((u16)(v2.x >> 16));
            float m20 = bf2f((u16)(v2.y & 0xffff)), m21 = bf2f((u16)(v2.y >> 16));

            sq.x += wq0 * xq0;  sq.y += wq1 * xq1;
            float tR0 = wR0 * xR0, tR1 = wR1 * xR1;
            float tm0 = wm0 * xm0, tm1 = wm1 * xm1;
            s0.x += tR0 * d0 + tm0 * m00;  s0.y += tR1 * d0 + tm1 * m01;
            s1.x += tR0 * d1 + tm0 * m10;  s1.y += tR1 * d1 + tm1 * m11;
            s2.x += tR0 * d2 + tm0 * m20;  s2.y += tR1 * d2 + tm1 * m21;
        }
    }
    NTST2<BF>(out, (size_t)a * F + fo, sq);
    NTST2<BF>(out, ob + (size_t)a * F3 + fo,       s0);
    NTST2<BF>(out, ob + (size_t)a * F3 + 128 + fo, s1);
    NTST2<BF>(out, ob + (size_t)a * F3 + 256 + fo, s2);
}
__global__ __launch_bounds__(256) void gfused_kernel(
    const void* q, const void* mu, const u16* wbf,
    const u16* xm12, const int4* ej4, const int* offsets,
    void* out, int n_atoms, int E, const int* flag)
{
    if (*flag) gfused_body<true >(q, mu, wbf, xm12, ej4, offsets, out, n_atoms, E);
    else       gfused_body<false>(q, mu, wbf, xm12, ej4, offsets, out, n_atoms, E);
}

// ---------------------------------------------------------------------------
extern "C" void kernel_launch(void* const* d_in, const int* in_sizes, int n_in,
                              void* d_out, int out_size, void* d_ws, size_t ws_size,
                              hipStream_t stream)
{
    const void* q   = d_in[0];
    const void* mu  = d_in[1];
    const void* Wij = d_in[2];
    const void* dir = d_in[3];
    const void* W1  = d_in[4];
    const void* b1  = d_in[5];
    const void* W2  = d_in[6];
    const void* b2  = d_in[7];
    const int* idx_i = (const int*)d_in[8];
    const int* idx_j = (const int*)d_in[9];

    const int n_atoms = in_sizes[0] / F;        // 50000
    const int E       = in_sizes[8];            // 500000
    const int eBlocks   = (E + 255) / 256;
    const int ewBlocks  = (E + 3) / 4;          // wave-per-edge grids
    const int gBlocks   = (n_atoms + 3) / 4;
    const int mlpBlocks = (n_atoms + TA - 1) / TA;

    // ws layout (~475 MB; ws ≈ 3 GB per poison-fill WRITE_SIZE evidence):
    //   wbf u16[E*384] | xm12 u16[A*768] | flag[4] | counts[A] | cursor[A]
    //   | offsets[A+1] | ej4 int4[E]
    u16*  wbf     = (u16*)d_ws;
    u16*  xm12    = wbf + (size_t)E * F3;
    int*  flag    = (int*)(xm12 + (size_t)n_atoms * ROW);
    int*  counts  = flag + 4;
    int*  cursor  = counts + n_atoms;
    int*  offsets = cursor + n_atoms;
    int4* ej4     = (int4*)(((size_t)(offsets + n_atoms + 1) + 15) & ~(size_t)15);

    detect_kernel<<<1, 256, 0, stream>>>(q, flag);
    hipMemsetAsync(counts, 0, (size_t)2 * n_atoms * sizeof(int), stream);
    count_kernel<<<eBlocks, 256, 0, stream>>>(idx_i, counts, E);
    scan_kernel<<<1, 1024, 0, stream>>>(counts, offsets, n_atoms);
    scatter_w_kernel<<<ewBlocks, 256, 0, stream>>>(idx_i, idx_j, dir, Wij, offsets,
                                                   cursor, ej4, wbf, E, flag);

    mu12_kernel<<<gBlocks, 256, 0, stream>>>(mu, xm12, n_atoms, flag);
    mlpfull_kernel<<<mlpBlocks, 256, 0, stream>>>(q, W1, b1, W2, b2, xm12, n_atoms, flag);

    gfused_kernel<<<gBlocks, 256, 0, stream>>>(q, mu, wbf, xm12, ej4, offsets,
                                               d_out, n_atoms, E, flag);
}

// Round 9
// 556.872 us; speedup vs baseline: 1.4385x; 1.4385x over previous
//
#include <hip/hip_runtime.h>

typedef unsigned short u16;
typedef unsigned int   u32;
typedef unsigned long long u64;

#define F 128
#define F3 384
#define ROW 768        // xm12 row length in u16 (1536 B): 64 pairs x 12
#define KP 136         // padded LDS k-stride (u16): 272 B, 16B-aligned rows

typedef __attribute__((ext_vector_type(8))) short bf16x8;
typedef __attribute__((ext_vector_type(4))) float f32x4;

__device__ __forceinline__ float bf2f(u16 v) {
    union { u32 u; float f; } c; c.u = ((u32)v) << 16; return c.f;
}
__device__ __forceinline__ u16 f2bf(float f) {
    union { float fv; u32 u; } c; c.fv = f;
    u32 u = c.u;
    return (u16)((u + 0x7fffu + ((u >> 16) & 1u)) >> 16);   // round-nearest-even
}
__device__ __forceinline__ float u2f(u32 v) {
    union { u32 u; float f; } c; c.u = v; return c.f;
}
__device__ __forceinline__ u32 f2u(float v) {
    union { float f; u32 u; } c; c.f = v; return c.u;
}
__device__ __forceinline__ u32 pk(float a, float b) {
    return ((u32)f2bf(b) << 16) | f2bf(a);
}

// dtype-generic accessors: BF=true -> bf16 (u16) arrays, false -> f32 arrays
template<bool BF> __device__ __forceinline__ float LD(const void* p, size_t i) {
    return BF ? bf2f(((const u16*)p)[i]) : ((const float*)p)[i];
}
template<bool BF> __device__ __forceinline__ float2 LD2(const void* p, size_t i) {
    if (BF) {
        u32 v = *(const u32*)((const u16*)p + i);
        float2 r; r.x = bf2f((u16)(v & 0xffff)); r.y = bf2f((u16)(v >> 16)); return r;
    }
    return *(const float2*)((const float*)p + i);
}
template<bool BF> __device__ __forceinline__ float4 LD4(const void* p, size_t i) {
    if (BF) {
        uint2 v = *(const uint2*)((const u16*)p + i);
        float4 r;
        r.x = bf2f((u16)(v.x & 0xffff)); r.y = bf2f((u16)(v.x >> 16));
        r.z = bf2f((u16)(v.y & 0xffff)); r.w = bf2f((u16)(v.y >> 16));
        return r;
    }
    return *(const float4*)((const float*)p + i);
}
template<bool BF> __device__ __forceinline__ void NTST2(void* p, size_t i, float2 v) {
    if (BF) {
        u32 o = pk(v.x, v.y);
        __builtin_nontemporal_store(o, (u32*)((u16*)p + i));
    } else {
        u64 o = ((u64)f2u(v.y) << 32) | f2u(v.x);
        __builtin_nontemporal_store(o, (u64*)((float*)p + i));
    }
}
template<bool BF> __device__ __forceinline__ float2 NTLD2(const void* p, size_t i) {
    if (BF) {
        u32 v = __builtin_nontemporal_load((const u32*)((const u16*)p + i));
        float2 r; r.x = bf2f((u16)(v & 0xffff)); r.y = bf2f((u16)(v >> 16)); return r;
    } else {
        u64 v = __builtin_nontemporal_load((const u64*)((const float*)p + i));
        float2 r; r.x = u2f((u32)v); r.y = u2f((u32)(v >> 32)); return r;
    }
}

// ---------------------------------------------------------------------------
// Dtype detector (proven)
// ---------------------------------------------------------------------------
__global__ __launch_bounds__(256) void detect_kernel(const void* q, int* flag) {
    __shared__ int cnt;
    if (threadIdx.x == 0) cnt = 0;
    __syncthreads();
    const u16* p = (const u16*)q;
    int c = 0;
    for (int i = threadIdx.x; i < 1024; i += 256) {
        u16 v = p[2 * i];
        int e = (v >> 7) & 0xFF;
        if (e >= 100 && e <= 150) c++;
    }
    atomicAdd(&cnt, c);
    __syncthreads();
    if (threadIdx.x == 0) *flag = (cnt > 512) ? 1 : 0;
}

// ---------------------------------------------------------------------------
// mu -> packed half of xm12: entries [6..11] of each 12-u16 pair-block (r7)
// ---------------------------------------------------------------------------
template<bool BF>
__device__ void mu12_body(const void* mu, u16* xm12, int n_atoms) {
    int a = blockIdx.x * 4 + (threadIdx.x >> 6);
    int p = threadIdx.x & 63;
    if (a >= n_atoms) return;
    float2 m0 = LD2<BF>(mu, (size_t)a * F3 + 2 * p);
    float2 m1 = LD2<BF>(mu, (size_t)a * F3 + 128 + 2 * p);
    float2 m2 = LD2<BF>(mu, (size_t)a * F3 + 256 + 2 * p);
    u16* base = xm12 + (size_t)a * ROW + p * 12;
    *(u32*)(base + 6) = pk(m0.x, m0.y);
    *(uint2*)(base + 8) = make_uint2(pk(m1.x, m1.y), pk(m2.x, m2.y));
}
__global__ __launch_bounds__(256) void mu12_kernel(const void* mu, u16* xm12,
                                                   int n_atoms, const int* flag) {
    if (*flag) mu12_body<true >(mu, xm12, n_atoms);
    else       mu12_body<false>(mu, xm12, n_atoms);
}

// ---------------------------------------------------------------------------
// MFMA MLP: 32 atoms/block, 256 thr = 4 waves. mfma_f32_16x16x32_bf16.
// Wave wv: row-tile (wv&1), col-tiles (wv>>1)*4 .. +3. K=128 = 4 steps.
// q,h staged [32][KP] bf16; W staged transposed [col][k] in shared wT buffer
// (W1, then W2 chunk-by-chunk). Emits packed x into xm12 slots [0..5].
// C/D layout (verified m89): col=lane&15, row=(lane>>4)*4+reg.
// A/B frags: 8 contiguous k per lane, k = kk*32 + (lane>>4)*8 + j.
// ---------------------------------------------------------------------------
template<bool BF>
__device__ void mlpfull_body(const void* q, const void* W1, const void* b1,
                             const void* W2, const void* b2,
                             u16* __restrict__ xm12, int n_atoms)
{
    __shared__ u16 qbf[32][KP];    // 8.5 KB
    __shared__ u16 wT [128][KP];   // 34 KB (W1, then W2 chunks)
    __shared__ u16 hbf[32][KP];    // 8.5 KB

    const int tid  = threadIdx.x;
    const int a0   = blockIdx.x * 32;
    const int wv   = tid >> 6;
    const int lane = tid & 63;
    const int lr   = lane & 15;
    const int lg   = lane >> 4;
    const int rowt = wv & 1;
    const int cbase= (wv >> 1) * 4;

    // ---- stage q -> qbf (bf16)
    for (int i = tid; i < 32 * 32; i += 256) {
        int a = i >> 5, k4 = (i & 31) * 4;
        float4 v = (a0 + a < n_atoms) ? LD4<BF>(q, (size_t)(a0 + a) * F + k4)
                                      : make_float4(0, 0, 0, 0);
        *(uint2*)&qbf[a][k4] = make_uint2(pk(v.x, v.y), pk(v.z, v.w));
    }
    // ---- stage W1 -> wT transposed (wT[col][k] = W1[k][col])
    for (int i = tid; i < 128 * 32; i += 256) {
        int col = i & 127, k4 = (i >> 7) * 4;
        float v0 = LD<BF>(W1, (size_t)(k4 + 0) * F + col);
        float v1 = LD<BF>(W1, (size_t)(k4 + 1) * F + col);
        float v2 = LD<BF>(W1, (size_t)(k4 + 2) * F + col);
        float v3 = LD<BF>(W1, (size_t)(k4 + 3) * F + col);
        *(uint2*)&wT[col][k4] = make_uint2(pk(v0, v1), pk(v2, v3));
    }
    __syncthreads();

    // ---- phase 1: h = silu(q@W1 + b1)
    bf16x8 af[4];
#pragma unroll
    for (int kk = 0; kk < 4; ++kk)
        af[kk] = *(const bf16x8*)&qbf[rowt * 16 + lr][kk * 32 + lg * 8];

#pragma unroll
    for (int ct = 0; ct < 4; ++ct) {
        int colt = cbase + ct;
        f32x4 acc = {0.0f, 0.0f, 0.0f, 0.0f};
#pragma unroll
        for (int kk = 0; kk < 4; ++kk) {
            bf16x8 bv = *(const bf16x8*)&wT[colt * 16 + lr][kk * 32 + lg * 8];
            acc = __builtin_amdgcn_mfma_f32_16x16x32_bf16(af[kk], bv, acc, 0, 0, 0);
        }
        int col = colt * 16 + lr;
        float bb = LD<BF>(b1, col);
#pragma unroll
        for (int r = 0; r < 4; ++r) {
            float h = acc[r] + bb;
            float s = h / (1.0f + __expf(-h));
            hbf[rowt * 16 + lg * 4 + r][col] = f2bf(s);
        }
    }
    __syncthreads();   // hbf complete; phase-1 wT reads complete

    // ---- phase 2: x = h @ W2 + b2, 3 col chunks through the same wT buffer
#pragma unroll
    for (int kk = 0; kk < 4; ++kk)
        af[kk] = *(const bf16x8*)&hbf[rowt * 16 + lr][kk * 32 + lg * 8];

    for (int cb = 0; cb < 3; ++cb) {
        for (int i = tid; i < 128 * 32; i += 256) {
            int col = i & 127, k4 = (i >> 7) * 4;
            float v0 = LD<BF>(W2, (size_t)(k4 + 0) * F3 + cb * 128 + col);
            float v1 = LD<BF>(W2, (size_t)(k4 + 1) * F3 + cb * 128 + col);
            float v2 = LD<BF>(W2, (size_t)(k4 + 2) * F3 + cb * 128 + col);
            float v3 = LD<BF>(W2, (size_t)(k4 + 3) * F3 + cb * 128 + col);
            *(uint2*)&wT[col][k4] = make_uint2(pk(v0, v1), pk(v2, v3));
        }
        __syncthreads();
#pragma unroll
        for (int ct = 0; ct < 4; ++ct) {
            int colt = cbase + ct;
            f32x4 acc = {0.0f, 0.0f, 0.0f, 0.0f};
#pragma unroll
            for (int kk = 0; kk < 4; ++kk) {
                bf16x8 bv = *(const bf16x8*)&wT[colt * 16 + lr][kk * 32 + lg * 8];
                acc = __builtin_amdgcn_mfma_f32_16x16x32_bf16(af[kk], bv, acc, 0, 0, 0);
            }
            int f = colt * 16 + lr;
            float bb = LD<BF>(b2, cb * 128 + f);
#pragma unroll
            for (int r = 0; r < 4; ++r) {
                int ga = a0 + rowt * 16 + lg * 4 + r;
                if (ga < n_atoms)
                    xm12[(size_t)ga * ROW + (f >> 1) * 12 + (f & 1) + 2 * cb]
                        = f2bf(acc[r] + bb);
            }
        }
        __syncthreads();   // wT reads complete before next restage
    }
}
__global__ __launch_bounds__(256) void mlpfull_kernel(
    const void* q, const void* W1, const void* b1, const void* W2, const void* b2,
    u16* xm12, int n_atoms, const int* flag)
{
    if (*flag) mlpfull_body<true >(q, W1, b1, W2, b2, xm12, n_atoms);
    else       mlpfull_body<false>(q, W1, b1, W2, b2, xm12, n_atoms);
}

// ---------------------------------------------------------------------------
// CSR build (round-7 proven): count -> scan -> scatter ej4
// ---------------------------------------------------------------------------
__global__ __launch_bounds__(256) void count_kernel(
    const int* __restrict__ idx_i, int* __restrict__ counts, int E)
{
    int e = blockIdx.x * 256 + threadIdx.x;
    if (e < E) atomicAdd(&counts[idx_i[e]], 1);
}

__global__ __launch_bounds__(1024) void scan_kernel(
    const int* __restrict__ counts, int* __restrict__ offsets, int n)
{
    __shared__ int buf[1024];
    const int t = threadIdx.x;
    const int m = (n + 1023) >> 10;
    const int i0 = t * m;
    int s = 0;
    for (int r = 0; r < m; ++r) {
        int i = i0 + r;
        if (i < n) s += counts[i];
    }
    buf[t] = s;
    __syncthreads();
    for (int off = 1; off < 1024; off <<= 1) {
        int add = (t >= off) ? buf[t - off] : 0;
        __syncthreads();
        buf[t] += add;
        __syncthreads();
    }
    int run = buf[t] - s;
    for (int r = 0; r < m; ++r) {
        int i = i0 + r;
        if (i < n) { offsets[i] = run; run += counts[i]; }
    }
    if (t == 1023) offsets[n] = buf[1023];
}

template<bool BF>
__device__ void scatter_body(const int* __restrict__ idx_i, const int* __restrict__ idx_j,
                             const void* __restrict__ dir, const int* __restrict__ offsets,
                             int* __restrict__ cursor, int4* __restrict__ ej4, int E)
{
    int e = blockIdx.x * 256 + threadIdx.x;
    if (e < E) {
        int i = idx_i[e];
        int pos = offsets[i] + atomicAdd(&cursor[i], 1);
        float d0 = LD<BF>(dir, (size_t)e * 3 + 0);
        float d1 = LD<BF>(dir, (size_t)e * 3 + 1);
        float d2 = LD<BF>(dir, (size_t)e * 3 + 2);
        int4 v;
        v.x = e;
        v.y = idx_j[e];
        v.z = (int)pk(d0, d1);
        v.w = (int)(u32)f2bf(d2);
        ej4[pos] = v;
    }
}
__global__ __launch_bounds__(256) void scatter_kernel(
    const int* idx_i, const int* idx_j, const void* dir, const int* offsets,
    int* cursor, int4* ej4, int E, const int* flag)
{
    if (*flag) scatter_body<true >(idx_i, idx_j, dir, offsets, cursor, ej4, E);
    else       scatter_body<false>(idx_i, idx_j, dir, offsets, cursor, ej4, E);
}

// ---------------------------------------------------------------------------
// FUSED gather (round-7 proven, byte-identical)
// ---------------------------------------------------------------------------
template<bool BF>
__device__ void gfused_body(const void* q, const void* mu, const void* Wij,
                            const u16* __restrict__ xm12,
                            const int4* __restrict__ ej4,
                            const int* __restrict__ offsets,
                            void* out, int n_atoms, int E)
{
    int a    = blockIdx.x * 4 + (threadIdx.x >> 6);
    int lane = threadIdx.x & 63;
    if (a >= n_atoms) return;
    const size_t fo = 2 * lane;
    const size_t ob = (size_t)n_atoms * F;

    float2 sq = LD2<BF>(q, (size_t)a * F + fo);
    float2 s0 = LD2<BF>(mu, (size_t)a * F3 + fo);
    float2 s1 = LD2<BF>(mu, (size_t)a * F3 + 128 + fo);
    float2 s2 = LD2<BF>(mu, (size_t)a * F3 + 256 + fo);

    int k0 = offsets[a], k1 = offsets[a + 1];
    for (int kb = k0; kb < k1; kb += 64) {
        int cnt = k1 - kb; if (cnt > 64) cnt = 64;
        int e_r = 0, j_r = 0, d01_r = 0, d2_r = 0;
        if (lane < cnt) {
            int4 t = ej4[kb + lane];
            e_r = t.x; if ((unsigned)e_r >= (unsigned)E) e_r = 0;
            j_r = t.y; if ((unsigned)j_r >= (unsigned)n_atoms) j_r = 0;
            d01_r = t.z; d2_r = t.w;
        }
#pragma unroll 4
        for (int c = 0; c < cnt; ++c) {
            int e   = __shfl(e_r, c, 64);
            int j   = __shfl(j_r, c, 64);
            int d01 = __shfl(d01_r, c, 64);
            int d2i = __shfl(d2_r, c, 64);
            float d0 = bf2f((u16)((u32)d01 & 0xffff));
            float d1 = bf2f((u16)((u32)d01 >> 16));
            float d2 = bf2f((u16)((u32)d2i & 0xffff));

            float2 wq = NTLD2<BF>(Wij, (size_t)e * F3 + fo);
            float2 wR = NTLD2<BF>(Wij, (size_t)e * F3 + 128 + fo);
            float2 wm = NTLD2<BF>(Wij, (size_t)e * F3 + 256 + fo);

            const u16* row = xm12 + (size_t)j * ROW + lane * 12;
            uint2 v0 = *(const uint2*)(row);
            uint2 v1 = *(const uint2*)(row + 4);
            uint2 v2 = *(const uint2*)(row + 8);

            float xq0 = bf2f((u16)(v0.x & 0xffff)), xq1 = bf2f((u16)(v0.x >> 16));
            float xR0 = bf2f((u16)(v0.y & 0xffff)), xR1 = bf2f((u16)(v0.y >> 16));
            float xm0 = bf2f((u16)(v1.x & 0xffff)), xm1 = bf2f((u16)(v1.x >> 16));
            float m00 = bf2f((u16)(v1.y & 0xffff)), m01 = bf2f((u16)(v1.y >> 16));
            float m10 = bf2f((u16)(v2.x & 0xffff)), m11 = bf2f((u16)(v2.x >> 16));
            float m20 = bf2f((u16)(v2.y & 0xffff)), m21 = bf2f((u16)(v2.y >> 16));

            sq.x += wq.x * xq0;  sq.y += wq.y * xq1;
            float tR0 = wR.x * xR0, tR1 = wR.y * xR1;
            float tm0 = wm.x * xm0, tm1 = wm.y * xm1;
            s0.x += tR0 * d0 + tm0 * m00;  s0.y += tR1 * d0 + tm1 * m01;
            s1.x += tR0 * d1 + tm0 * m10;  s1.y += tR1 * d1 + tm1 * m11;
            s2.x += tR0 * d2 + tm0 * m20;  s2.y += tR1 * d2 + tm1 * m21;
        }
    }
    NTST2<BF>(out, (size_t)a * F + fo, sq);
    NTST2<BF>(out, ob + (size_t)a * F3 + fo,       s0);
    NTST2<BF>(out, ob + (size_t)a * F3 + 128 + fo, s1);
    NTST2<BF>(out, ob + (size_t)a * F3 + 256 + fo, s2);
}
__global__ __launch_bounds__(256) void gfused_kernel(
    const void* q, const void* mu, const void* Wij,
    const u16* xm12, const int4* ej4, const int* offsets,
    void* out, int n_atoms, int E, const int* flag)
{
    if (*flag) gfused_body<true >(q, mu, Wij, xm12, ej4, offsets, out, n_atoms, E);
    else       gfused_body<false>(q, mu, Wij, xm12, ej4, offsets, out, n_atoms, E);
}

// ---------------------------------------------------------------------------
extern "C" void kernel_launch(void* const* d_in, const int* in_sizes, int n_in,
                              void* d_out, int out_size, void* d_ws, size_t ws_size,
                              hipStream_t stream)
{
    const void* q   = d_in[0];
    const void* mu  = d_in[1];
    const void* Wij = d_in[2];
    const void* dir = d_in[3];
    const void* W1  = d_in[4];
    const void* b1  = d_in[5];
    const void* W2  = d_in[6];
    const void* b2  = d_in[7];
    const int* idx_i = (const int*)d_in[8];
    const int* idx_j = (const int*)d_in[9];

    const int n_atoms = in_sizes[0] / F;        // 50000
    const int E       = in_sizes[8];            // 500000
    const int eBlocks   = (E + 255) / 256;
    const int gBlocks   = (n_atoms + 3) / 4;
    const int mlpBlocks = (n_atoms + 31) / 32;

    // ws layout (~90 MB):
    //   xm12 u16[A*768] | flag[4] | counts[A] | cursor[A] | offsets[A+1] | ej4 int4[E]
    u16*  xm12    = (u16*)d_ws;
    int*  flag    = (int*)(xm12 + (size_t)n_atoms * ROW);
    int*  counts  = flag + 4;
    int*  cursor  = counts + n_atoms;
    int*  offsets = cursor + n_atoms;
    int4* ej4     = (int4*)(((size_t)(offsets + n_atoms + 1) + 15) & ~(size_t)15);

    detect_kernel<<<1, 256, 0, stream>>>(q, flag);
    hipMemsetAsync(counts, 0, (size_t)2 * n_atoms * sizeof(int), stream);
    count_kernel<<<eBlocks, 256, 0, stream>>>(idx_i, counts, E);
    scan_kernel<<<1, 1024, 0, stream>>>(counts, offsets, n_atoms);
    scatter_kernel<<<eBlocks, 256, 0, stream>>>(idx_i, idx_j, dir, offsets,
                                                cursor, ej4, E, flag);

    mu12_kernel<<<gBlocks, 256, 0, stream>>>(mu, xm12, n_atoms, flag);
    mlpfull_kernel<<<mlpBlocks, 256, 0, stream>>>(q, W1, b1, W2, b2, xm12, n_atoms, flag);

    gfused_kernel<<<gBlocks, 256, 0, stream>>>(q, mu, Wij, xm12, ej4, offsets,
                                               d_out, n_atoms, E, flag);
}

// Round 10
// 553.736 us; speedup vs baseline: 1.4467x; 1.0057x over previous
//
#include <hip/hip_runtime.h>

typedef unsigned short u16;
typedef unsigned int   u32;
typedef unsigned long long u64;

#define F 128
#define F3 384
#define ROW 768        // xm12 row length in u16 (1536 B): 64 pairs x 12
#define KP 136         // padded LDS k-stride (u16): 272 B, 16B-aligned rows

typedef __attribute__((ext_vector_type(8))) short bf16x8;
typedef __attribute__((ext_vector_type(4))) float f32x4;

__device__ __forceinline__ float bf2f(u16 v) {
    union { u32 u; float f; } c; c.u = ((u32)v) << 16; return c.f;
}
__device__ __forceinline__ u16 f2bf(float f) {
    union { float fv; u32 u; } c; c.fv = f;
    u32 u = c.u;
    return (u16)((u + 0x7fffu + ((u >> 16) & 1u)) >> 16);   // round-nearest-even
}
__device__ __forceinline__ float u2f(u32 v) {
    union { u32 u; float f; } c; c.u = v; return c.f;
}
__device__ __forceinline__ u32 f2u(float v) {
    union { float f; u32 u; } c; c.f = v; return c.u;
}
__device__ __forceinline__ u32 pk(float a, float b) {
    return ((u32)f2bf(b) << 16) | f2bf(a);
}

// dtype-generic accessors: BF=true -> bf16 (u16) arrays, false -> f32 arrays
template<bool BF> __device__ __forceinline__ float LD(const void* p, size_t i) {
    return BF ? bf2f(((const u16*)p)[i]) : ((const float*)p)[i];
}
template<bool BF> __device__ __forceinline__ float2 LD2(const void* p, size_t i) {
    if (BF) {
        u32 v = *(const u32*)((const u16*)p + i);
        float2 r; r.x = bf2f((u16)(v & 0xffff)); r.y = bf2f((u16)(v >> 16)); return r;
    }
    return *(const float2*)((const float*)p + i);
}
template<bool BF> __device__ __forceinline__ float4 LD4(const void* p, size_t i) {
    if (BF) {
        uint2 v = *(const uint2*)((const u16*)p + i);
        float4 r;
        r.x = bf2f((u16)(v.x & 0xffff)); r.y = bf2f((u16)(v.x >> 16));
        r.z = bf2f((u16)(v.y & 0xffff)); r.w = bf2f((u16)(v.y >> 16));
        return r;
    }
    return *(const float4*)((const float*)p + i);
}
template<bool BF> __device__ __forceinline__ void NTST2(void* p, size_t i, float2 v) {
    if (BF) {
        u32 o = pk(v.x, v.y);
        __builtin_nontemporal_store(o, (u32*)((u16*)p + i));
    } else {
        u64 o = ((u64)f2u(v.y) << 32) | f2u(v.x);
        __builtin_nontemporal_store(o, (u64*)((float*)p + i));
    }
}
template<bool BF> __device__ __forceinline__ float2 NTLD2(const void* p, size_t i) {
    if (BF) {
        u32 v = __builtin_nontemporal_load((const u32*)((const u16*)p + i));
        float2 r; r.x = bf2f((u16)(v & 0xffff)); r.y = bf2f((u16)(v >> 16)); return r;
    } else {
        u64 v = __builtin_nontemporal_load((const u64*)((const float*)p + i));
        float2 r; r.x = u2f((u32)v); r.y = u2f((u32)(v >> 32)); return r;
    }
}

// ---------------------------------------------------------------------------
// Fused detect + count: block 0 = dtype detector; blocks 1..eBlocks = count.
// ---------------------------------------------------------------------------
__global__ __launch_bounds__(256) void detect_count_kernel(
    const void* q, int* flag, const int* __restrict__ idx_i,
    int* __restrict__ counts, int E)
{
    if (blockIdx.x == 0) {
        __shared__ int cnt;
        if (threadIdx.x == 0) cnt = 0;
        __syncthreads();
        const u16* p = (const u16*)q;
        int c = 0;
        for (int i = threadIdx.x; i < 1024; i += 256) {
            u16 v = p[2 * i];
            int e = (v >> 7) & 0xFF;
            if (e >= 100 && e <= 150) c++;
        }
        atomicAdd(&cnt, c);
        __syncthreads();
        if (threadIdx.x == 0) *flag = (cnt > 512) ? 1 : 0;
    } else {
        int e = (blockIdx.x - 1) * 256 + threadIdx.x;
        if (e < E) atomicAdd(&counts[idx_i[e]], 1);
    }
}

// ---------------------------------------------------------------------------
// Single-block scan (round-7 proven)
// ---------------------------------------------------------------------------
__global__ __launch_bounds__(1024) void scan_kernel(
    const int* __restrict__ counts, int* __restrict__ offsets, int n)
{
    __shared__ int buf[1024];
    const int t = threadIdx.x;
    const int m = (n + 1023) >> 10;
    const int i0 = t * m;
    int s = 0;
    for (int r = 0; r < m; ++r) {
        int i = i0 + r;
        if (i < n) s += counts[i];
    }
    buf[t] = s;
    __syncthreads();
    for (int off = 1; off < 1024; off <<= 1) {
        int add = (t >= off) ? buf[t - off] : 0;
        __syncthreads();
        buf[t] += add;
        __syncthreads();
    }
    int run = buf[t] - s;
    for (int r = 0; r < m; ++r) {
        int i = i0 + r;
        if (i < n) { offsets[i] = run; run += counts[i]; }
    }
    if (t == 1023) offsets[n] = buf[1023];
}

// ---------------------------------------------------------------------------
// Fused scatter + mu12: blocks [0, eBlocks) scatter ej4; the rest do mu12.
// ---------------------------------------------------------------------------
template<bool BF>
__device__ void scatter_part(const int* __restrict__ idx_i, const int* __restrict__ idx_j,
                             const void* __restrict__ dir, const int* __restrict__ offsets,
                             int* __restrict__ cursor, int4* __restrict__ ej4, int E)
{
    int e = blockIdx.x * 256 + threadIdx.x;
    if (e < E) {
        int i = idx_i[e];
        int pos = offsets[i] + atomicAdd(&cursor[i], 1);
        float d0 = LD<BF>(dir, (size_t)e * 3 + 0);
        float d1 = LD<BF>(dir, (size_t)e * 3 + 1);
        float d2 = LD<BF>(dir, (size_t)e * 3 + 2);
        int4 v;
        v.x = e;
        v.y = idx_j[e];
        v.z = (int)pk(d0, d1);
        v.w = (int)(u32)f2bf(d2);
        ej4[pos] = v;
    }
}
template<bool BF>
__device__ void mu12_part(const void* mu, u16* xm12, int n_atoms, int bid) {
    int a = bid * 4 + (threadIdx.x >> 6);
    int p = threadIdx.x & 63;
    if (a >= n_atoms) return;
    float2 m0 = LD2<BF>(mu, (size_t)a * F3 + 2 * p);
    float2 m1 = LD2<BF>(mu, (size_t)a * F3 + 128 + 2 * p);
    float2 m2 = LD2<BF>(mu, (size_t)a * F3 + 256 + 2 * p);
    u16* base = xm12 + (size_t)a * ROW + p * 12;
    *(u32*)(base + 6) = pk(m0.x, m0.y);
    *(uint2*)(base + 8) = make_uint2(pk(m1.x, m1.y), pk(m2.x, m2.y));
}
__global__ __launch_bounds__(256) void scatter_mu12_kernel(
    const int* idx_i, const int* idx_j, const void* dir, const int* offsets,
    int* cursor, int4* ej4, int E, const void* mu, u16* xm12, int n_atoms,
    int eBlocks, const int* flag)
{
    if ((int)blockIdx.x < eBlocks) {
        if (*flag) scatter_part<true >(idx_i, idx_j, dir, offsets, cursor, ej4, E);
        else       scatter_part<false>(idx_i, idx_j, dir, offsets, cursor, ej4, E);
    } else {
        int bid = blockIdx.x - eBlocks;
        if (*flag) mu12_part<true >(mu, xm12, n_atoms, bid);
        else       mu12_part<false>(mu, xm12, n_atoms, bid);
    }
}

// ---------------------------------------------------------------------------
// MFMA MLP (round-9 proven): 32 atoms/block, mfma_f32_16x16x32_bf16.
// ---------------------------------------------------------------------------
template<bool BF>
__device__ void mlpfull_body(const void* q, const void* W1, const void* b1,
                             const void* W2, const void* b2,
                             u16* __restrict__ xm12, int n_atoms)
{
    __shared__ u16 qbf[32][KP];
    __shared__ u16 wT [128][KP];
    __shared__ u16 hbf[32][KP];

    const int tid  = threadIdx.x;
    const int a0   = blockIdx.x * 32;
    const int wv   = tid >> 6;
    const int lane = tid & 63;
    const int lr   = lane & 15;
    const int lg   = lane >> 4;
    const int rowt = wv & 1;
    const int cbase= (wv >> 1) * 4;

    for (int i = tid; i < 32 * 32; i += 256) {
        int a = i >> 5, k4 = (i & 31) * 4;
        float4 v = (a0 + a < n_atoms) ? LD4<BF>(q, (size_t)(a0 + a) * F + k4)
                                      : make_float4(0, 0, 0, 0);
        *(uint2*)&qbf[a][k4] = make_uint2(pk(v.x, v.y), pk(v.z, v.w));
    }
    for (int i = tid; i < 128 * 32; i += 256) {
        int col = i & 127, k4 = (i >> 7) * 4;
        float v0 = LD<BF>(W1, (size_t)(k4 + 0) * F + col);
        float v1 = LD<BF>(W1, (size_t)(k4 + 1) * F + col);
        float v2 = LD<BF>(W1, (size_t)(k4 + 2) * F + col);
        float v3 = LD<BF>(W1, (size_t)(k4 + 3) * F + col);
        *(uint2*)&wT[col][k4] = make_uint2(pk(v0, v1), pk(v2, v3));
    }
    __syncthreads();

    bf16x8 af[4];
#pragma unroll
    for (int kk = 0; kk < 4; ++kk)
        af[kk] = *(const bf16x8*)&qbf[rowt * 16 + lr][kk * 32 + lg * 8];

#pragma unroll
    for (int ct = 0; ct < 4; ++ct) {
        int colt = cbase + ct;
        f32x4 acc = {0.0f, 0.0f, 0.0f, 0.0f};
#pragma unroll
        for (int kk = 0; kk < 4; ++kk) {
            bf16x8 bv = *(const bf16x8*)&wT[colt * 16 + lr][kk * 32 + lg * 8];
            acc = __builtin_amdgcn_mfma_f32_16x16x32_bf16(af[kk], bv, acc, 0, 0, 0);
        }
        int col = colt * 16 + lr;
        float bb = LD<BF>(b1, col);
#pragma unroll
        for (int r = 0; r < 4; ++r) {
            float h = acc[r] + bb;
            float s = h / (1.0f + __expf(-h));
            hbf[rowt * 16 + lg * 4 + r][col] = f2bf(s);
        }
    }
    __syncthreads();

#pragma unroll
    for (int kk = 0; kk < 4; ++kk)
        af[kk] = *(const bf16x8*)&hbf[rowt * 16 + lr][kk * 32 + lg * 8];

    for (int cb = 0; cb < 3; ++cb) {
        for (int i = tid; i < 128 * 32; i += 256) {
            int col = i & 127, k4 = (i >> 7) * 4;
            float v0 = LD<BF>(W2, (size_t)(k4 + 0) * F3 + cb * 128 + col);
            float v1 = LD<BF>(W2, (size_t)(k4 + 1) * F3 + cb * 128 + col);
            float v2 = LD<BF>(W2, (size_t)(k4 + 2) * F3 + cb * 128 + col);
            float v3 = LD<BF>(W2, (size_t)(k4 + 3) * F3 + cb * 128 + col);
            *(uint2*)&wT[col][k4] = make_uint2(pk(v0, v1), pk(v2, v3));
        }
        __syncthreads();
#pragma unroll
        for (int ct = 0; ct < 4; ++ct) {
            int colt = cbase + ct;
            f32x4 acc = {0.0f, 0.0f, 0.0f, 0.0f};
#pragma unroll
            for (int kk = 0; kk < 4; ++kk) {
                bf16x8 bv = *(const bf16x8*)&wT[colt * 16 + lr][kk * 32 + lg * 8];
                acc = __builtin_amdgcn_mfma_f32_16x16x32_bf16(af[kk], bv, acc, 0, 0, 0);
            }
            int f = colt * 16 + lr;
            float bb = LD<BF>(b2, cb * 128 + f);
#pragma unroll
            for (int r = 0; r < 4; ++r) {
                int ga = a0 + rowt * 16 + lg * 4 + r;
                if (ga < n_atoms)
                    xm12[(size_t)ga * ROW + (f >> 1) * 12 + (f & 1) + 2 * cb]
                        = f2bf(acc[r] + bb);
            }
        }
        __syncthreads();
    }
}
__global__ __launch_bounds__(256) void mlpfull_kernel(
    const void* q, const void* W1, const void* b1, const void* W2, const void* b2,
    u16* xm12, int n_atoms, const int* flag)
{
    if (*flag) mlpfull_body<true >(q, W1, b1, W2, b2, xm12, n_atoms);
    else       mlpfull_body<false>(q, W1, b1, W2, b2, xm12, n_atoms);
}

// ---------------------------------------------------------------------------
// FUSED gather (round-7 proven; unroll 4 -> 8 for deeper load pipelining)
// ---------------------------------------------------------------------------
template<bool BF>
__device__ void gfused_body(const void* q, const void* mu, const void* Wij,
                            const u16* __restrict__ xm12,
                            const int4* __restrict__ ej4,
                            const int* __restrict__ offsets,
                            void* out, int n_atoms, int E)
{
    int a    = blockIdx.x * 4 + (threadIdx.x >> 6);
    int lane = threadIdx.x & 63;
    if (a >= n_atoms) return;
    const size_t fo = 2 * lane;
    const size_t ob = (size_t)n_atoms * F;

    float2 sq = LD2<BF>(q, (size_t)a * F + fo);
    float2 s0 = LD2<BF>(mu, (size_t)a * F3 + fo);
    float2 s1 = LD2<BF>(mu, (size_t)a * F3 + 128 + fo);
    float2 s2 = LD2<BF>(mu, (size_t)a * F3 + 256 + fo);

    int k0 = offsets[a], k1 = offsets[a + 1];
    for (int kb = k0; kb < k1; kb += 64) {
        int cnt = k1 - kb; if (cnt > 64) cnt = 64;
        int e_r = 0, j_r = 0, d01_r = 0, d2_r = 0;
        if (lane < cnt) {
            int4 t = ej4[kb + lane];
            e_r = t.x; if ((unsigned)e_r >= (unsigned)E) e_r = 0;
            j_r = t.y; if ((unsigned)j_r >= (unsigned)n_atoms) j_r = 0;
            d01_r = t.z; d2_r = t.w;
        }
#pragma unroll 8
        for (int c = 0; c < cnt; ++c) {
            int e   = __shfl(e_r, c, 64);
            int j   = __shfl(j_r, c, 64);
            int d01 = __shfl(d01_r, c, 64);
            int d2i = __shfl(d2_r, c, 64);
            float d0 = bf2f((u16)((u32)d01 & 0xffff));
            float d1 = bf2f((u16)((u32)d01 >> 16));
            float d2 = bf2f((u16)((u32)d2i & 0xffff));

            float2 wq = NTLD2<BF>(Wij, (size_t)e * F3 + fo);
            float2 wR = NTLD2<BF>(Wij, (size_t)e * F3 + 128 + fo);
            float2 wm = NTLD2<BF>(Wij, (size_t)e * F3 + 256 + fo);

            const u16* row = xm12 + (size_t)j * ROW + lane * 12;
            uint2 v0 = *(const uint2*)(row);
            uint2 v1 = *(const uint2*)(row + 4);
            uint2 v2 = *(const uint2*)(row + 8);

            float xq0 = bf2f((u16)(v0.x & 0xffff)), xq1 = bf2f((u16)(v0.x >> 16));
            float xR0 = bf2f((u16)(v0.y & 0xffff)), xR1 = bf2f((u16)(v0.y >> 16));
            float xm0 = bf2f((u16)(v1.x & 0xffff)), xm1 = bf2f((u16)(v1.x >> 16));
            float m00 = bf2f((u16)(v1.y & 0xffff)), m01 = bf2f((u16)(v1.y >> 16));
            float m10 = bf2f((u16)(v2.x & 0xffff)), m11 = bf2f((u16)(v2.x >> 16));
            float m20 = bf2f((u16)(v2.y & 0xffff)), m21 = bf2f((u16)(v2.y >> 16));

            sq.x += wq.x * xq0;  sq.y += wq.y * xq1;
            float tR0 = wR.x * xR0, tR1 = wR.y * xR1;
            float tm0 = wm.x * xm0, tm1 = wm.y * xm1;
            s0.x += tR0 * d0 + tm0 * m00;  s0.y += tR1 * d0 + tm1 * m01;
            s1.x += tR0 * d1 + tm0 * m10;  s1.y += tR1 * d1 + tm1 * m11;
            s2.x += tR0 * d2 + tm0 * m20;  s2.y += tR1 * d2 + tm1 * m21;
        }
    }
    NTST2<BF>(out, (size_t)a * F + fo, sq);
    NTST2<BF>(out, ob + (size_t)a * F3 + fo,       s0);
    NTST2<BF>(out, ob + (size_t)a * F3 + 128 + fo, s1);
    NTST2<BF>(out, ob + (size_t)a * F3 + 256 + fo, s2);
}
__global__ __launch_bounds__(256) void gfused_kernel(
    const void* q, const void* mu, const void* Wij,
    const u16* xm12, const int4* ej4, const int* offsets,
    void* out, int n_atoms, int E, const int* flag)
{
    if (*flag) gfused_body<true >(q, mu, Wij, xm12, ej4, offsets, out, n_atoms, E);
    else       gfused_body<false>(q, mu, Wij, xm12, ej4, offsets, out, n_atoms, E);
}

// ---------------------------------------------------------------------------
extern "C" void kernel_launch(void* const* d_in, const int* in_sizes, int n_in,
                              void* d_out, int out_size, void* d_ws, size_t ws_size,
                              hipStream_t stream)
{
    const void* q   = d_in[0];
    const void* mu  = d_in[1];
    const void* Wij = d_in[2];
    const void* dir = d_in[3];
    const void* W1  = d_in[4];
    const void* b1  = d_in[5];
    const void* W2  = d_in[6];
    const void* b2  = d_in[7];
    const int* idx_i = (const int*)d_in[8];
    const int* idx_j = (const int*)d_in[9];

    const int n_atoms = in_sizes[0] / F;        // 50000
    const int E       = in_sizes[8];            // 500000
    const int eBlocks   = (E + 255) / 256;
    const int gBlocks   = (n_atoms + 3) / 4;
    const int mlpBlocks = (n_atoms + 31) / 32;

    // ws layout (~90 MB):
    //   xm12 u16[A*768] | flag[4] | counts[A] | cursor[A] | offsets[A+1] | ej4 int4[E]
    u16*  xm12    = (u16*)d_ws;
    int*  flag    = (int*)(xm12 + (size_t)n_atoms * ROW);
    int*  counts  = flag + 4;
    int*  cursor  = counts + n_atoms;
    int*  offsets = cursor + n_atoms;
    int4* ej4     = (int4*)(((size_t)(offsets + n_atoms + 1) + 15) & ~(size_t)15);

    hipMemsetAsync(counts, 0, (size_t)2 * n_atoms * sizeof(int), stream);
    detect_count_kernel<<<eBlocks + 1, 256, 0, stream>>>(q, flag, idx_i, counts, E);
    scan_kernel<<<1, 1024, 0, stream>>>(counts, offsets, n_atoms);
    scatter_mu12_kernel<<<eBlocks + gBlocks, 256, 0, stream>>>(
        idx_i, idx_j, dir, offsets, cursor, ej4, E, mu, xm12, n_atoms, eBlocks, flag);

    mlpfull_kernel<<<mlpBlocks, 256, 0, stream>>>(q, W1, b1, W2, b2, xm12, n_atoms, flag);

    gfused_kernel<<<gBlocks, 256, 0, stream>>>(q, mu, Wij, xm12, ej4, offsets,
                                               d_out, n_atoms, E, flag);
}